// Round 4
// baseline (216.291 us; speedup 1.0000x reference)
//
#include <hip/hip_runtime.h>
#include <hip/hip_bf16.h>

#define N_PTS (4096 * 192)

typedef __bf16 bf16x8 __attribute__((ext_vector_type(8)));
typedef float  f32x16 __attribute__((ext_vector_type(16)));
typedef float  f32x4  __attribute__((ext_vector_type(4)));
typedef float  f32x2  __attribute__((ext_vector_type(2)));

// ws layout (bf16 element offsets). Main tiles are [m][k'] with k rows permuted
// by kinv (32x32x16 chain: C-layout of layer l == B-frag layout of layer l+1)
// AND column-chunk XOR-swizzled (16B slot s -> s ^ (m&15)) so a LINEAR
// global_load_lds copy yields a bank-conflict-free LDS image for ds_read_b128
// at 256B row stride (read applies the same XOR).
#define W1P 0          // 128x128
#define W2P 16384      // 128x128 (rows 0..127 of w2)
#define W3P 32768      // 128x128
#define WFP 49152      // 128x128
#define WRP 65536      // 64x128
#define W0E 73728      // 128x16  fixup vs posb (natural f rows, k16 = posb space)
#define W2E 75776      // 128x16
#define WRE 77824      // 64x16
#define WDE 78848      // 2x128   row0 = wd_hi[kinv], row1 = wd_lo[kinv]
#define WOE 79104      // 8x64    rows0-2 = wo_hi ch, rows4-6 = wo_lo ch
// total span = 79616 bf16 = 159,232 B

__device__ __forceinline__ int kinv(int k) {
  // stored row k -> source feature p, for the 32x32x16 chain:
  // p = mt*32 + q*8 + h*4 + r  <->  k = (2mt + (q>>1))*16 + h*8 + (q&1)*4 + r
  int c = k >> 4, h = (k >> 3) & 1, e = k & 7;
  int mt = c >> 1, q = (c & 1) * 2 + (e >> 2), r = e & 3;
  return mt * 32 + q * 8 + h * 4 + r;
}

__global__ void prep_kernel(const float* __restrict__ w0, const float* __restrict__ w1,
                            const float* __restrict__ w2, const float* __restrict__ w3,
                            const float* __restrict__ wf, const float* __restrict__ wr,
                            const float* __restrict__ wd, const float* __restrict__ wo,
                            __bf16* __restrict__ ws) {
  int i = blockIdx.x * 256 + threadIdx.x;
  if (i < 65536) {                       // w1,w2,w3,wf main tiles: k-permuted + swizzled
    int t = i >> 14, j = i & 16383, m = j >> 7, col = j & 127;
    int k = (((col >> 3) ^ (m & 15)) << 3) | (col & 7);
    int p = kinv(k);
    const float* w = (t == 0) ? w1 : (t == 1) ? w2 : (t == 2) ? w3 : wf;
    ws[i] = (__bf16)w[p * 128 + m];
  } else if (i < 73728) {                // wr main tile
    int j = i - 65536, m = j >> 7, col = j & 127;
    int k = (((col >> 3) ^ (m & 15)) << 3) | (col & 7);
    int p = kinv(k);
    ws[i] = (__bf16)wr[p * 64 + m];
  } else if (i < 75776) {                // W0E (k-space = posb, no permutation)
    int j = i - 73728, f = j >> 4, k = j & 15; float v = 0.f;
    if (k < 3)      v = w0[k * 128 + f];
    else if (k < 6) v = w0[(k - 3) * 128 + f];
    else if (k < 9) { float w = w0[(k - 6) * 128 + f]; v = w - (float)(__bf16)w; }
    ws[i] = (__bf16)v;
  } else if (i < 77824) {                // W2E
    int j = i - 75776, f = j >> 4, k = j & 15; float v = 0.f;
    if (k < 3)      v = w2[(128 + k) * 128 + f];
    else if (k < 6) v = w2[(128 + k - 3) * 128 + f];
    else if (k < 9) { float w = w2[(128 + k - 6) * 128 + f]; v = w - (float)(__bf16)w; }
    ws[i] = (__bf16)v;
  } else if (i < 78848) {                // WRE
    int j = i - 77824, n = j >> 4, k = j & 15; float v = 0.f;
    if (k >= 9 && k < 15) v = wr[(128 + ((k - 9) % 3)) * 64 + n];
    ws[i] = (__bf16)v;
  } else if (i < 79104) {                // WDE: wd hi/lo, k-permuted
    int j = i - 78848, row = j >> 7, k = j & 127, p = kinv(k);
    float v = wd[p];
    ws[i] = (row == 0) ? (__bf16)v : (__bf16)(v - (float)(__bf16)v);
  } else if (i < 79616) {                // WOE: wo hi/lo, k64-permuted
    int j = i - 79104, row = j >> 6, k = j & 63, p = kinv(k);
    float v = 0.f;
    if (row < 3)                 v = wo[p * 3 + row];
    else if (row >= 4 && row < 7) { float w = wo[p * 3 + row - 4]; v = w - (float)(__bf16)w; }
    ws[i] = (__bf16)v;
  }
}

template <int BASE>
__device__ __forceinline__ bf16x8 pack_relu(const f32x16& a) {
  bf16x8 v;
#pragma unroll
  for (int r = 0; r < 8; ++r) v[r] = (__bf16)fmaxf(a[BASE + r], 0.f);
  return v;
}

// Cooperative global->LDS stage of NB bytes (256 threads, 16B/lane/round).
template <int NB>
__device__ __forceinline__ void stage_tile(const __bf16* __restrict__ gsrc,
                                           __bf16* lds, int wv, int lane) {
  const char* g = (const char*)gsrc;
  char* l = (char*)lds;
#pragma unroll
  for (int r = 0; r < NB; r += 4096) {
    const char* src = g + r + wv * 1024 + lane * 16;
    char* dst = l + r + wv * 1024;                        // wave-uniform base
    __builtin_amdgcn_global_load_lds(
        (const __attribute__((address_space(1))) void*)src,
        (__attribute__((address_space(3))) void*)dst, 16, 0, 0);
  }
}

// One layer from LDS-resident swizzled weights; 32x32x16 MFMA, K=128,
// activations entirely in registers. hin/hout chunks: c holds stored-k
// [c*16, c*16+16); lane (row,h) elem e of chunk c = stored-k c*16+h*8+e.
template <int NM, bool FIX>
__device__ __forceinline__ void mlayer(const __bf16* __restrict__ wlds,
                                       const float* __restrict__ bias,
                                       const __bf16* __restrict__ wext,
                                       const bf16x8 (&pf)[2],
                                       const bf16x8 (&hin)[8][2],
                                       bf16x8 (&hout)[2 * NM][2],
                                       int row, int h) {
#pragma unroll
  for (int mt = 0; mt < NM; ++mt) {
    f32x16 a0, a1;
#pragma unroll
    for (int q = 0; q < 4; ++q) {
      f32x4 bv = *(const f32x4*)(bias + mt * 32 + q * 8 + h * 4);
#pragma unroll
      for (int r = 0; r < 4; ++r) { a0[q * 4 + r] = bv[r]; a1[q * 4 + r] = bv[r]; }
    }
#pragma unroll
    for (int c = 0; c < 8; ++c) {
      bf16x8 w = *(const bf16x8*)(wlds + (mt * 32 + row) * 128 +
                                  (((c * 2 + h) ^ (row & 15)) << 3));
      a0 = __builtin_amdgcn_mfma_f32_32x32x16_bf16(w, hin[c][0], a0, 0, 0, 0);
      a1 = __builtin_amdgcn_mfma_f32_32x32x16_bf16(w, hin[c][1], a1, 0, 0, 0);
    }
    if constexpr (FIX) {
      bf16x8 w = *(const bf16x8*)(wext + (mt * 32 + row) * 16 + h * 8);
      a0 = __builtin_amdgcn_mfma_f32_32x32x16_bf16(w, pf[0], a0, 0, 0, 0);
      a1 = __builtin_amdgcn_mfma_f32_32x32x16_bf16(w, pf[1], a1, 0, 0, 0);
    }
    hout[2 * mt][0]     = pack_relu<0>(a0);
    hout[2 * mt + 1][0] = pack_relu<8>(a0);
    hout[2 * mt][1]     = pack_relu<0>(a1);
    hout[2 * mt + 1][1] = pack_relu<8>(a1);
  }
}

__global__ __launch_bounds__(256, 2) void nerf_kernel(
    const float* __restrict__ x,
    const float* __restrict__ b0, const float* __restrict__ b1,
    const float* __restrict__ b2, const float* __restrict__ b3,
    const float* __restrict__ bd, const float* __restrict__ bfv,
    const float* __restrict__ br, const float* __restrict__ bo,
    const __bf16* __restrict__ ws,
    float* __restrict__ out) {
  __shared__ __align__(16) __bf16 posb[256 * 16];   //  8 KiB
  __shared__ __align__(16) __bf16 sA[128 * 128];    // 32 KiB
  __shared__ __align__(16) __bf16 sB[128 * 128];    // 32 KiB  (72K -> 2 blk/CU)

  const int tid  = threadIdx.x;
  const int wv   = tid >> 6;
  const int lane = tid & 63;
  const int row  = lane & 31;      // M/N index within 32-tile
  const int h    = lane >> 5;      // k-half
  const int p0   = blockIdx.x * 256;
  const int pw   = wv * 64;

  // ---- issue W1->A, W2->B prefetch first (hidden under posb+layer0)
  stage_tile<32768>(ws + W1P, sA, wv, lane);
  stage_tile<32768>(ws + W2P, sB, wv, lane);

  // ---- stage posb (one point/thread; wave-local, no barrier needed)
  {
    const float* xp = x + (size_t)(p0 + tid) * 6;
    f32x2 a = *(const f32x2*)xp;
    f32x2 b = *(const f32x2*)(xp + 2);
    f32x2 c = *(const f32x2*)(xp + 4);
    float px = a[0], py = a[1], pz = b[0], vx = b[1], vy = c[0], vz = c[1];
    __bf16 phx = (__bf16)px, phy = (__bf16)py, phz = (__bf16)pz;
    __bf16 vhx = (__bf16)vx, vhy = (__bf16)vy, vhz = (__bf16)vz;
    __bf16 plx = (__bf16)(px - (float)phx), ply = (__bf16)(py - (float)phy), plz = (__bf16)(pz - (float)phz);
    __bf16 vlx = (__bf16)(vx - (float)vhx), vly = (__bf16)(vy - (float)vhy), vlz = (__bf16)(vz - (float)vhz);
    bf16x8 r0, r1;
    r0[0] = phx; r0[1] = phy; r0[2] = phz; r0[3] = plx; r0[4] = ply; r0[5] = plz; r0[6] = phx; r0[7] = phy;
    r1[0] = phz; r1[1] = vhx; r1[2] = vhy; r1[3] = vhz; r1[4] = vlx; r1[5] = vly; r1[6] = vlz; r1[7] = (__bf16)0.f;
    *(bf16x8*)(posb + tid * 16) = r0;
    *(bf16x8*)(posb + tid * 16 + 8) = r1;
  }

  // ---- preload l0 fixup A-frags (K=16 exact: all lanes active)
  bf16x8 w0f[4];
#pragma unroll
  for (int mt = 0; mt < 4; ++mt)
    w0f[mt] = *(const bf16x8*)(ws + W0E + (mt * 32 + row) * 16 + h * 8);

  // ---- per-wave pos/vdir B-frags: point = nt*32+row, k = h*8+e
  bf16x8 pf[2];
#pragma unroll
  for (int nt = 0; nt < 2; ++nt)
    pf[nt] = *(const bf16x8*)(posb + (pw + nt * 32 + row) * 16 + h * 8);

  bf16x8 hA[8][2], hB[8][2];

  // ---- layer 0: h0 = relu(pos @ w0 + b0), one K=16 MFMA per (mt,nt)
#pragma unroll
  for (int mt = 0; mt < 4; ++mt) {
    f32x16 a0, a1;
#pragma unroll
    for (int q = 0; q < 4; ++q) {
      f32x4 bv = *(const f32x4*)(b0 + mt * 32 + q * 8 + h * 4);
#pragma unroll
      for (int r = 0; r < 4; ++r) { a0[q * 4 + r] = bv[r]; a1[q * 4 + r] = bv[r]; }
    }
    a0 = __builtin_amdgcn_mfma_f32_32x32x16_bf16(w0f[mt], pf[0], a0, 0, 0, 0);
    a1 = __builtin_amdgcn_mfma_f32_32x32x16_bf16(w0f[mt], pf[1], a1, 0, 0, 0);
    hA[2 * mt][0]     = pack_relu<0>(a0);
    hA[2 * mt + 1][0] = pack_relu<8>(a0);
    hA[2 * mt][1]     = pack_relu<0>(a1);
    hA[2 * mt + 1][1] = pack_relu<8>(a1);
  }
  __syncthreads();                                   // W1(A), W2(B) staged & visible

  // ---- layer 1 from A
  mlayer<4, false>(sA, b1, nullptr, pf, hA, hB, row, h);
  __syncthreads();                                   // all waves done with A
  stage_tile<32768>(ws + W3P, sA, wv, lane);

  // ---- layer 2 from B (+pos fixup); W3 staging lands underneath
  mlayer<4, true>(sB, b2, ws + W2E, pf, hB, hA, row, h);
  __syncthreads();                                   // W3(A) visible, B free
  stage_tile<32768>(ws + WFP, sB, wv, lane);

  // ---- layer 3 from A; WF staging lands underneath
  mlayer<4, false>(sA, b3, nullptr, pf, hA, hB, row, h);
  __syncthreads();                                   // WF(B) visible, A free
  stage_tile<16384>(ws + WRP, sA, wv, lane);

  // ---- density = relu(h3 @ wd + bd): A row0=hi, row1=lo (C rows 0,1 on h=0)
  {
    f32x16 a0, a1;
#pragma unroll
    for (int r = 0; r < 16; ++r) { a0[r] = 0.f; a1[r] = 0.f; }
    int dr = (row == 1) ? 128 : 0;
#pragma unroll
    for (int c = 0; c < 8; ++c) {
      bf16x8 ad = *(const bf16x8*)(ws + WDE + dr + c * 16 + h * 8);
      a0 = __builtin_amdgcn_mfma_f32_32x32x16_bf16(ad, hB[c][0], a0, 0, 0, 0);
      a1 = __builtin_amdgcn_mfma_f32_32x32x16_bf16(ad, hB[c][1], a1, 0, 0, 0);
    }
    if (h == 0) {
      float bdv = bd[0];
      out[(size_t)3 * N_PTS + p0 + pw + row]      = fmaxf(a0[0] + a0[1] + bdv, 0.f);
      out[(size_t)3 * N_PTS + p0 + pw + 32 + row] = fmaxf(a1[0] + a1[1] + bdv, 0.f);
    }
  }

  // ---- features = relu(h3 @ wf + bf) from B; WR staging lands underneath
  mlayer<4, false>(sB, bfv, nullptr, pf, hB, hA, row, h);
  __syncthreads();                                   // WR(A) visible

  // ---- r = relu([feat, vdir] @ wr + br) from A, 64 outputs
  bf16x8 hR[4][2];
  mlayer<2, true>(sA, br, ws + WRE, pf, hA, hR, row, h);

  // ---- rgb = sigmoid(r @ wo + bo): hi ch in regs0-2 (h=0), lo in regs0-2 (h=1)
  {
    f32x16 a0, a1;
#pragma unroll
    for (int r = 0; r < 16; ++r) { a0[r] = 0.f; a1[r] = 0.f; }
    int orow = (row & 7) * 64;
#pragma unroll
    for (int c = 0; c < 4; ++c) {
      bf16x8 ao = *(const bf16x8*)(ws + WOE + orow + c * 16 + h * 8);
      a0 = __builtin_amdgcn_mfma_f32_32x32x16_bf16(ao, hR[c][0], a0, 0, 0, 0);
      a1 = __builtin_amdgcn_mfma_f32_32x32x16_bf16(ao, hR[c][1], a1, 0, 0, 0);
    }
    float s00 = a0[0] + __shfl_xor(a0[0], 32, 64);
    float s01 = a0[1] + __shfl_xor(a0[1], 32, 64);
    float s02 = a0[2] + __shfl_xor(a0[2], 32, 64);
    float s10 = a1[0] + __shfl_xor(a1[0], 32, 64);
    float s11 = a1[1] + __shfl_xor(a1[1], 32, 64);
    float s12 = a1[2] + __shfl_xor(a1[2], 32, 64);
    if (h == 0) {
      float bo0 = bo[0], bo1 = bo[1], bo2 = bo[2];
      size_t o0 = (size_t)(p0 + pw + row) * 3;
      out[o0 + 0] = 1.f / (1.f + __expf(-(s00 + bo0)));
      out[o0 + 1] = 1.f / (1.f + __expf(-(s01 + bo1)));
      out[o0 + 2] = 1.f / (1.f + __expf(-(s02 + bo2)));
      size_t o1 = (size_t)(p0 + pw + 32 + row) * 3;
      out[o1 + 0] = 1.f / (1.f + __expf(-(s10 + bo0)));
      out[o1 + 1] = 1.f / (1.f + __expf(-(s11 + bo1)));
      out[o1 + 2] = 1.f / (1.f + __expf(-(s12 + bo2)));
    }
  }
}

extern "C" void kernel_launch(void* const* d_in, const int* in_sizes, int n_in,
                              void* d_out, int out_size, void* d_ws, size_t ws_size,
                              hipStream_t stream) {
  const float* x  = (const float*)d_in[0];
  const float* w0 = (const float*)d_in[1];
  const float* b0 = (const float*)d_in[2];
  const float* w1 = (const float*)d_in[3];
  const float* b1 = (const float*)d_in[4];
  const float* w2 = (const float*)d_in[5];
  const float* b2 = (const float*)d_in[6];
  const float* w3 = (const float*)d_in[7];
  const float* b3 = (const float*)d_in[8];
  const float* wd = (const float*)d_in[9];
  const float* bd = (const float*)d_in[10];
  const float* wf = (const float*)d_in[11];
  const float* bfv= (const float*)d_in[12];
  const float* wr = (const float*)d_in[13];
  const float* br = (const float*)d_in[14];
  const float* wo = (const float*)d_in[15];
  const float* bo = (const float*)d_in[16];
  __bf16* ws = (__bf16*)d_ws;
  float* out = (float*)d_out;

  prep_kernel<<<311, 256, 0, stream>>>(w0, w1, w2, w3, wf, wr, wd, wo, ws);
  nerf_kernel<<<N_PTS / 256, 256, 0, stream>>>(x, b0, b1, b2, b3, bd, bfv, br, bo, ws, out);
}